// Round 7
// baseline (385.043 us; speedup 1.0000x reference)
//
#include <hip/hip_runtime.h>
#include <math.h>

#define DIM   4096
#define NEXP  64
#define MB    16               // tokens per block
#define KC    128              // k per LDS stage (elements)
#define NST   (DIM / KC)       // 32 stages
#define STAGE_FLOATS (MB * KC) // 2048 floats = 8 KB per buffer

typedef _Float16 f16x8 __attribute__((ext_vector_type(8)));
typedef float    f32x4 __attribute__((ext_vector_type(4)));

#define GLOBAL_LOAD_LDS16(gp, lp)                                              \
    __builtin_amdgcn_global_load_lds(                                          \
        (const __attribute__((address_space(1))) void*)(gp),                   \
        (__attribute__((address_space(3))) void*)(lp), 16, 0, 0)

// ---- Kernel 0: pack W -> fp16 hi/lo planes in MFMA B-fragment order --------
// wp[nt(4)][ck(128)][lane(64)][j(8)]; lane = quad*16 + n
__global__ __launch_bounds__(256)
void pack_w_kernel(const float* __restrict__ W,
                   _Float16* __restrict__ wph, _Float16* __restrict__ wpl) {
    const int flat = blockIdx.x * 256 + threadIdx.x;   // nt*8192 + ck*64 + lane
    const int lane = flat & 63;
    const int ck   = (flat >> 6) & 127;
    const int nt   = flat >> 13;
    const int e    = nt * 16 + (lane & 15);
    const int k0   = ck * 32 + (lane >> 4) * 8;
    const float* src = W + ((size_t)e << 12) + k0;
    float4 v0 = *(const float4*)(src);
    float4 v1 = *(const float4*)(src + 4);
    float vv[8] = {v0.x, v0.y, v0.z, v0.w, v1.x, v1.y, v1.z, v1.w};
    f16x8 hi, lo;
#pragma unroll
    for (int i = 0; i < 8; ++i) {
        _Float16 hh = (_Float16)vv[i];
        hi[i] = hh;
        lo[i] = (_Float16)(vv[i] - (float)hh);   // exact residual
    }
    *(f16x8*)(wph + (size_t)flat * 8) = hi;
    *(f16x8*)(wpl + (size_t)flat * 8) = lo;
}

// ---- Kernel 1: fused gate, no-drain pipelined K-loop -----------------------
// Block: 256 thr = 4 waves; wave wv = 16-expert n-group, all 16 tokens.
// h staged fp32 via global_load_lds into 3 rotating buffers, 2 stages ahead;
// raw s_barrier + manual vmcnt keeps prefetches alive across the barrier.
// Steady-state invariant: each inter-barrier region issues exactly 10 VMEM ops
// (2 DMA + 8 B); vmcnt(10) at the top of iter c therefore drains everything
// older than region c-1 — in particular DMA(c) — independent of intra-region
// issue order. The prologue is hard-drained (vmcnt(0)) to bootstrap this.
// LDS layout (per stage): addr(t, g) = (g*16 + (t^g))*32 bytes, g = k-8-group.
__global__ __launch_bounds__(256, 4)
void gate_mfma_kernel(const float* __restrict__ h,
                      const _Float16* __restrict__ wph,
                      const _Float16* __restrict__ wpl,
                      float* __restrict__ out, int n_tokens) {
    __shared__ float ABUF[3 * STAGE_FLOATS];   // 24 KB
    __shared__ float lg[MB][NEXP + 4];         // 4.3 KB

    const int tid  = threadIdx.x;
    const int lane = tid & 63;
    const int wv   = __builtin_amdgcn_readfirstlane(tid >> 6);  // n-group 0..3
    const int l15  = lane & 15;
    const int quad = lane >> 4;
    const int t0   = blockIdx.x * MB;

    // ---- DMA source mapping: instr j = wv*2+i covers g in {2j, 2j+1} ------
    // lane = g0*32 + tau*2 + hh ; row = tau ^ g ; src byte = row*16KB + g*32 + hh*16
    const int g0  = lane >> 5;
    const int tau = (lane >> 1) & 15;
    const int hh  = lane & 1;
    const char* hbase = (const char*)(h + (size_t)t0 * DIM);
    const char* gsrc[2];
    char* ldst[2];
#pragma unroll
    for (int i = 0; i < 2; ++i) {
        int j = wv * 2 + i;
        int g = 2 * j + g0;
        int row = tau ^ g;
        gsrc[i] = hbase + (size_t)row * (DIM * 4) + g * 32 + hh * 16;
        ldst[i] = (char*)ABUF + j * 1024;     // + bufIdx*8192 at issue
    }

    // ---- B fragment base (packed): per stage 4 chunks x (hi,lo) -----------
    const _Float16* bph = wph + ((size_t)(wv * 128) * 64 + lane) * 8;
    const _Float16* bpl = wpl + ((size_t)(wv * 128) * 64 + lane) * 8;
    f16x8 Bh[2][4], Bl[2][4];

    // ---- prologue: DMA stages 0,1 then HARD DRAIN, then B stage 0 ---------
#pragma unroll
    for (int i = 0; i < 2; ++i) GLOBAL_LOAD_LDS16(gsrc[i], ldst[i]);                 // DMA(0)->b0
#pragma unroll
    for (int i = 0; i < 2; ++i) GLOBAL_LOAD_LDS16(gsrc[i] + 512, ldst[i] + 8192);    // DMA(1)->b1
    // Bootstrap drain: guarantees stages 0 and 1 are in LDS before the loop,
    // independent of how the compiler ordered the loads above.
    asm volatile("s_waitcnt vmcnt(0)" ::: "memory");
    __builtin_amdgcn_s_barrier();
#pragma unroll
    for (int s = 0; s < 4; ++s) {
        Bh[0][s] = *(const f16x8*)(bph + s * 512);
        Bl[0][s] = *(const f16x8*)(bpl + s * 512);
    }

    f32x4 acc = {0.f, 0.f, 0.f, 0.f};

#pragma unroll
    for (int c = 0; c < NST; ++c) {
        // steady state: newest 10 = region c-1 (DMA(c+1)+B(c)); all older drained
        asm volatile("s_waitcnt vmcnt(10)" ::: "memory");
        __builtin_amdgcn_s_barrier();

        // issue DMA(c+2) -> buffer (c+2)%3  (clamped at the tail)
        {
            const int sc = (c + 2 < NST) ? (c + 2) : (NST - 1);
            const int bi = (c + 2) % 3;
#pragma unroll
            for (int i = 0; i < 2; ++i)
                GLOBAL_LOAD_LDS16(gsrc[i] + (size_t)sc * 512, ldst[i] + bi * 8192);
        }
        // issue B(c+1) -> regs (clamped)
        {
            const int sb = (c + 1 < NST) ? (c + 1) : (NST - 1);
            const size_t boff = (size_t)sb * 4 * 512;
            const int nb = (c + 1) & 1;
#pragma unroll
            for (int s = 0; s < 4; ++s) {
                Bh[nb][s] = *(const f16x8*)(bph + boff + s * 512);
                Bl[nb][s] = *(const f16x8*)(bpl + boff + s * 512);
            }
        }

        // consume stage c from buffer c%3: read fp32 A, convert, MFMA
        const float* buf = ABUF + (c % 3) * STAGE_FLOATS;
        const int cb = c & 1;
#pragma unroll
        for (int s = 0; s < 4; ++s) {
            const int g = 4 * s + quad;
            const float* ap = buf + ((g * 16 + (l15 ^ g)) << 3);
            float4 p0 = *(const float4*)(ap);       // k j=0..3
            float4 p1 = *(const float4*)(ap + 4);   // k j=4..7
            float pv[8] = {p0.x, p0.y, p0.z, p0.w, p1.x, p1.y, p1.z, p1.w};
            f16x8 ah, al;
#pragma unroll
            for (int i = 0; i < 8; ++i) {
                _Float16 x = (_Float16)pv[i];
                ah[i] = x;
                al[i] = (_Float16)(pv[i] - (float)x);
            }
            acc = __builtin_amdgcn_mfma_f32_16x16x32_f16(ah, Bh[cb][s], acc, 0, 0, 0);
            acc = __builtin_amdgcn_mfma_f32_16x16x32_f16(al, Bh[cb][s], acc, 0, 0, 0);
            acc = __builtin_amdgcn_mfma_f32_16x16x32_f16(ah, Bl[cb][s], acc, 0, 0, 0);
        }
    }

    // ---- epilogue (full sync; drains leftover clamped prefetches) ---------
    __syncthreads();
#pragma unroll
    for (int r = 0; r < 4; ++r)
        lg[4 * quad + r][wv * 16 + l15] = acc[r];   // C/D: col=expert, row=token
    __syncthreads();

    if (tid < MB) {
        const float* row = lg[tid];
        float m = -INFINITY;
#pragma unroll 8
        for (int e = 0; e < NEXP; ++e) m = fmaxf(m, row[e]);
        float z = 0.0f, b1 = -INFINITY, b2 = -INFINITY;
        int i1 = 0, i2 = 0;
        for (int e = 0; e < NEXP; ++e) {
            float v = row[e];
            z += expf(v - m);
            if (v > b1)      { b2 = b1; i2 = i1; b1 = v; i1 = e; }
            else if (v > b2) { b2 = v; i2 = e; }
        }
        float g1 = expf(b1 - m), g2 = expf(b2 - m);
        float w1 = g1 / z, w2 = g2 / z;
        float ssum = w1 + w2 + 1e-9f;
        int t = t0 + tid;
        *(float2*)(out + 2 * t) = make_float2(w1 / ssum, w2 / ssum);
        *(float2*)(out + 2 * n_tokens + 2 * t) = make_float2((float)i1, (float)i2);
    }
}

extern "C" void kernel_launch(void* const* d_in, const int* in_sizes, int n_in,
                              void* d_out, int out_size, void* d_ws, size_t ws_size,
                              hipStream_t stream) {
    const float* h = (const float*)d_in[0];
    const float* W = (const float*)d_in[1];
    float* out = (float*)d_out;
    const int n_tokens = in_sizes[0] / DIM;        // 16384

    _Float16* wph = (_Float16*)d_ws;               // 512 KB packed hi
    _Float16* wpl = wph + (size_t)NEXP * DIM;      // 512 KB packed lo

    pack_w_kernel<<<(NEXP * DIM / 8) / 256, 256, 0, stream>>>(W, wph, wpl);
    gate_mfma_kernel<<<n_tokens / MB, 256, 0, stream>>>(h, wph, wpl, out, n_tokens);
}